// Round 2
// 877.408 us; speedup vs baseline: 1.1190x; 1.1190x over previous
//
#include <hip/hip_runtime.h>
#include <hip/hip_bf16.h>

#define DEV __device__ __forceinline__

typedef __attribute__((ext_vector_type(8))) short bf16x8;
typedef __attribute__((ext_vector_type(4))) float f32x4;

// ---------------------------------------------------------------- helpers
DEV unsigned short bfbits(float x) {
    __hip_bfloat16 b = __float2bfloat16(x);
    return __builtin_bit_cast(unsigned short, b);
}
DEV float b2f(unsigned short u) {
    __hip_bfloat16 b = __builtin_bit_cast(__hip_bfloat16, u);
    return __bfloat162float(b);
}

DEV void gl2lds16(const void* g, void* l) {
    __builtin_amdgcn_global_load_lds(
        (const __attribute__((address_space(1))) void*)g,
        (__attribute__((address_space(3))) void*)l,
        16, 0, 0);
}

#define WAIT_VM4()  asm volatile("s_waitcnt vmcnt(4)" ::: "memory")
#define WAIT_VM0()  asm volatile("s_waitcnt vmcnt(0)" ::: "memory")
#define BARRIER()   asm volatile("s_barrier"          ::: "memory")

// ---------------------------------------------------------------- fp32 -> bf16 convert
__global__ __launch_bounds__(256) void cvt_bf16(const float* __restrict__ in,
                                                unsigned short* __restrict__ out, int n) {
    int i = (blockIdx.x * 256 + threadIdx.x) * 4;
    if (i >= n) return;
    float4 f = *(const float4*)(in + i);
    ushort4 u;
    u.x = bfbits(f.x); u.y = bfbits(f.y); u.z = bfbits(f.z); u.w = bfbits(f.w);
    *(ushort4*)(out + i) = u;
}

// ---------------------------------------------------------------- 256x256 multi-phase GEMM (T1+T2+T3+T4+T5)
// C = A @ B^T (+bias). A:[M][768], B:[N][768] row-major bf16. K=768 fixed (12 tiles of 64).
// 8 waves (2M x 4N), per-wave out 128x64. BK=64 split into two K=32 halves.
// LDS (static, 128 KB): 2 bufs x {A.ks0, A.ks1, B.ks0, B.ks1} x 16 KB.
// Swizzle: 16B k-block ^= (row>>1)&3 (involution), applied on gl2lds *source*
// (linear LDS dest, rule #21) and on the ds_read address. Bank-slot
// 16(row&1)+4(quad^((row>>1)&3)) covers 8 slots exactly 2-way -> conflict-free.
// vmcnt discipline: queue at P1/P3 entry is [A0,A0,B0,B0,A1,A1,B1,B1]; vmcnt(4)
// retires exactly the half-tiles read in that phase pair. Never 0 in main loop.
// EPI=0: float C row-major + bias.  EPI=1: qkv epilogue (bias, q/k row-norm, head-major bf16).
template <int EPI>
__global__ __launch_bounds__(512, 2) void gemm256(
        const unsigned short* __restrict__ A,
        const unsigned short* __restrict__ B,
        const float* __restrict__ bias,
        float* __restrict__ Cf,
        unsigned short* __restrict__ qhat,
        unsigned short* __restrict__ khat,
        unsigned short* __restrict__ varr,
        int N) {
    constexpr int K = 768, NT = 12;
    __shared__ __align__(16) unsigned short sh[65536];     // 128 KB static
    const int t = threadIdx.x;
    const int wave = t >> 6, lane = t & 63;
    const int quad = lane >> 4, l16 = lane & 15;
    const int wm = wave >> 2, wn = wave & 3;               // 2 x 4 wave grid

    // T1: bijective XCD-chunk swizzle (nwg % 8 == 0 for both grids used here)
    const int gx = gridDim.x;
    const int nwg = gx * gridDim.y;
    const int wg0 = blockIdx.y * gx + blockIdx.x;
    const int swz = (wg0 & 7) * (nwg >> 3) + (wg0 >> 3);
    const int m0 = (swz / gx) * 256;
    const int n0 = (swz % gx) * 256;

    const unsigned short* Abase = A + (size_t)m0 * K;
    const unsigned short* Bbase = B + (size_t)n0 * K;

    // staging: thread t stages rows (t>>2) and (t>>2)+128, LDS k-block (t&3);
    // swizzled global source k-block = (t&3) ^ ((row>>1)&3) = (t&3)^((t>>3)&3),
    // constant per thread (128 % 8 == 0 keeps it valid for the +128 row too).
    const int scb = (t & 3) ^ ((t >> 3) & 3);
    const size_t soff = (size_t)(t >> 2) * K + scb * 8;
    auto STAGE = [&](const unsigned short* g, unsigned short* l) {
        gl2lds16(g + soff, l + t * 8);                  // rows 0..127   (linear dest)
        gl2lds16(g + soff + 128 * K, l + 4096 + t * 8); // rows 128..255
    };

    // fragment reads: row = 16*i + l16 (+wave base, mult of 64) -> (row>>1)&3 = (l16>>1)&3
    const int cb8 = (quad ^ ((l16 >> 1) & 3)) * 8;
    const int aoff = (wm * 128 + l16) * 32 + cb8;   // shorts into a half-tile
    const int boff = (wn * 64 + l16) * 32 + cb8;

    // prologue: tile 0, issue order A.ks0, B.ks0, A.ks1, B.ks1 (8 loads/thread)
    STAGE(Abase,      sh);
    STAGE(Bbase,      sh + 16384);
    STAGE(Abase + 32, sh + 8192);
    STAGE(Bbase + 32, sh + 24576);

    f32x4 acc[8][4] = {};

#pragma unroll 2
    for (int kt = 0; kt < NT; ++kt) {
        unsigned short* buf  = sh + (kt & 1) * 32768;
        unsigned short* nbuf = sh + ((kt + 1) & 1) * 32768;
        const unsigned short* An = Abase + (kt + 1) * 64;
        const unsigned short* Bn = Bbase + (kt + 1) * 64;
        bf16x8 afr[4], bfr[4];

        // -------- P1: ks0, i0..3
        WAIT_VM4();
        BARRIER();
#pragma unroll
        for (int i = 0; i < 4; i++) afr[i] = *(const bf16x8*)(buf + aoff + i * 512);
#pragma unroll
        for (int j = 0; j < 4; j++) bfr[j] = *(const bf16x8*)(buf + 16384 + boff + j * 512);
        if (kt + 1 < NT) STAGE(An, nbuf);                        // (t+1).A.ks0
        __builtin_amdgcn_s_setprio(1);
#pragma unroll
        for (int i = 0; i < 4; i++)
#pragma unroll
            for (int j = 0; j < 4; j++)
                acc[i][j] = __builtin_amdgcn_mfma_f32_16x16x32_bf16(afr[i], bfr[j], acc[i][j], 0, 0, 0);
        __builtin_amdgcn_s_setprio(0);

        // -------- P2: ks0, i4..7  (B frags reused in registers)
#pragma unroll
        for (int i = 0; i < 4; i++) afr[i] = *(const bf16x8*)(buf + aoff + (i + 4) * 512);
        if (kt + 1 < NT) STAGE(Bn, nbuf + 16384);                // (t+1).B.ks0
        __builtin_amdgcn_s_setprio(1);
#pragma unroll
        for (int i = 0; i < 4; i++)
#pragma unroll
            for (int j = 0; j < 4; j++)
                acc[i + 4][j] = __builtin_amdgcn_mfma_f32_16x16x32_bf16(afr[i], bfr[j], acc[i + 4][j], 0, 0, 0);
        __builtin_amdgcn_s_setprio(0);

        // -------- P3: ks1, i0..3
        if (kt + 1 < NT) { WAIT_VM4(); } else { WAIT_VM0(); }
        BARRIER();
#pragma unroll
        for (int i = 0; i < 4; i++) afr[i] = *(const bf16x8*)(buf + 8192 + aoff + i * 512);
#pragma unroll
        for (int j = 0; j < 4; j++) bfr[j] = *(const bf16x8*)(buf + 24576 + boff + j * 512);
        if (kt + 1 < NT) STAGE(An + 32, nbuf + 8192);            // (t+1).A.ks1
        __builtin_amdgcn_s_setprio(1);
#pragma unroll
        for (int i = 0; i < 4; i++)
#pragma unroll
            for (int j = 0; j < 4; j++)
                acc[i][j] = __builtin_amdgcn_mfma_f32_16x16x32_bf16(afr[i], bfr[j], acc[i][j], 0, 0, 0);
        __builtin_amdgcn_s_setprio(0);

        // -------- P4: ks1, i4..7
#pragma unroll
        for (int i = 0; i < 4; i++) afr[i] = *(const bf16x8*)(buf + 8192 + aoff + (i + 4) * 512);
        if (kt + 1 < NT) STAGE(Bn + 32, nbuf + 24576);           // (t+1).B.ks1
        __builtin_amdgcn_s_setprio(1);
#pragma unroll
        for (int i = 0; i < 4; i++)
#pragma unroll
            for (int j = 0; j < 4; j++)
                acc[i + 4][j] = __builtin_amdgcn_mfma_f32_16x16x32_bf16(afr[i], bfr[j], acc[i + 4][j], 0, 0, 0);
        __builtin_amdgcn_s_setprio(0);
    }

    // ---------------------------------------------------------------- epilogue
    const int colbase = n0 + wn * 64;
    if constexpr (EPI == 0) {
#pragma unroll
        for (int j = 0; j < 4; j++) {
            int col = colbase + j * 16 + l16;
            float bv = bias[col];
#pragma unroll
            for (int i = 0; i < 8; i++)
#pragma unroll
                for (int r = 0; r < 4; r++) {
                    int row = m0 + wm * 128 + i * 16 + quad * 4 + r;
                    Cf[(size_t)row * N + col] = acc[i][j][r] + bv;
                }
        }
    } else {
        // qkv epilogue: bias -> (q,k: row-norm) -> bf16 head-major [b,h,s,d]
        const int sec = colbase / 768;             // 0=q 1=k 2=v (64-col wave span never straddles)
        const int cin = colbase - sec * 768;
        const int h = cin >> 6;
        const int b = m0 >> 12;
        unsigned short* dst = (sec == 0) ? qhat : (sec == 1) ? khat : varr;
        const size_t headbase = (size_t)(b * 12 + h) * 4096;
        float bv[4];
#pragma unroll
        for (int j = 0; j < 4; j++) bv[j] = bias[colbase + j * 16 + l16];
#pragma unroll
        for (int i = 0; i < 8; i++) {
            float o[4][4];
#pragma unroll
            for (int j = 0; j < 4; j++)
#pragma unroll
                for (int r = 0; r < 4; r++) o[j][r] = acc[i][j][r] + bv[j];
            if (sec < 2) {
#pragma unroll
                for (int r = 0; r < 4; r++) {
                    float ss = o[0][r]*o[0][r] + o[1][r]*o[1][r] + o[2][r]*o[2][r] + o[3][r]*o[3][r];
                    ss += __shfl_xor(ss, 1, 64);
                    ss += __shfl_xor(ss, 2, 64);
                    ss += __shfl_xor(ss, 4, 64);
                    ss += __shfl_xor(ss, 8, 64);
                    float sc = rsqrtf(ss);
#pragma unroll
                    for (int j = 0; j < 4; j++) o[j][r] *= sc;
                }
            }
#pragma unroll
            for (int j = 0; j < 4; j++)
#pragma unroll
                for (int r = 0; r < 4; r++) {
                    int s = (m0 + wm * 128 + i * 16 + quad * 4 + r) & 4095;
                    dst[(headbase + s) * 64 + j * 16 + l16] = bfbits(o[j][r]);
                }
        }
    }
}

// ---------------------------------------------------------------- kv partials: kvpart[bh*4+chunk][e][f] = sum_s khat[s,e]*v[s,f]
__global__ __launch_bounds__(256) void kv_kernel(const unsigned short* __restrict__ khat,
                                                 const unsigned short* __restrict__ varr,
                                                 float* __restrict__ kvpart) {
    const int bh = blockIdx.x >> 2, chunk = blockIdx.x & 3;
    const int t = threadIdx.x, wave = t >> 6, lane = t & 63;
    __shared__ __align__(16) float kt[64 * 64];
    __shared__ __align__(16) float vt[64 * 64];
    const int e0 = (lane >> 3) * 8, f0 = (lane & 7) * 8;
    float acc[8][8] = {};

    for (int tile = 0; tile < 16; tile++) {
        int sbase = chunk * 1024 + tile * 64;
        __syncthreads();
#pragma unroll
        for (int i = 0; i < 2; i++) {
            int c = t + i * 256;                  // 0..511 chunk of 8 elems
            int row = c >> 3, off = (c & 7) * 8;
            size_t g = ((size_t)bh * 4096 + sbase + row) * 64 + off;
            bf16x8 kk = *(const bf16x8*)(khat + g);
            bf16x8 vv = *(const bf16x8*)(varr + g);
#pragma unroll
            for (int j = 0; j < 8; j++) {
                kt[row * 64 + off + j] = b2f((unsigned short)kk[j]);
                vt[row * 64 + off + j] = b2f((unsigned short)vv[j]);
            }
        }
        __syncthreads();
#pragma unroll
        for (int dsi = 0; dsi < 16; dsi++) {
            int ds = wave * 16 + dsi;
            f32x4 ka = *(f32x4*)&kt[ds * 64 + e0], kb = *(f32x4*)&kt[ds * 64 + e0 + 4];
            f32x4 va = *(f32x4*)&vt[ds * 64 + f0], vb = *(f32x4*)&vt[ds * 64 + f0 + 4];
            float ke[8] = {ka.x, ka.y, ka.z, ka.w, kb.x, kb.y, kb.z, kb.w};
            float vf[8] = {va.x, va.y, va.z, va.w, vb.x, vb.y, vb.z, vb.w};
#pragma unroll
            for (int i = 0; i < 8; i++)
#pragma unroll
                for (int j = 0; j < 8; j++) acc[i][j] += ke[i] * vf[j];
        }
    }
    __syncthreads();
    float* red = kt;
    for (int w = 0; w < 4; w++) {
        if (wave == w) {
#pragma unroll
            for (int i = 0; i < 8; i++)
#pragma unroll
                for (int j = 0; j < 8; j++) {
                    int idx = (e0 + i) * 64 + f0 + j;
                    if (w == 0) red[idx] = acc[i][j];
                    else        red[idx] += acc[i][j];
                }
        }
        __syncthreads();
    }
    float* outp = kvpart + (size_t)blockIdx.x * 4096;
#pragma unroll
    for (int i = 0; i < 16; i++) outp[t + i * 256] = red[t + i * 256];
}

// ---------------------------------------------------------------- reduce partials -> bf16 kvT[bh][f][e]
__global__ __launch_bounds__(256) void kvred_kernel(const float* __restrict__ kvpart,
                                                    unsigned short* __restrict__ kvT) {
    const int bh = blockIdx.x;
    const int t = threadIdx.x;
    __shared__ float kvf[64 * 65];
    const float* p0 = kvpart + (size_t)(bh * 4) * 4096;
#pragma unroll
    for (int i = 0; i < 16; i++) {
        int idx = t + i * 256;                 // e*64+f
        int e = idx >> 6, f = idx & 63;
        kvf[e * 65 + f] = p0[idx] + p0[4096 + idx] + p0[8192 + idx] + p0[12288 + idx];
    }
    __syncthreads();
#pragma unroll
    for (int i = 0; i < 16; i++) {
        int o = t + i * 256;                   // f*64+e
        int f = o >> 6, e = o & 63;
        kvT[(size_t)bh * 4096 + o] = bfbits(kvf[e * 65 + f]);
    }
}

// ---------------------------------------------------------------- attention: out = norm(0.5v + (1/pi) qhat@kv) + dconv(v)
__global__ __launch_bounds__(256) void attn_kernel(const unsigned short* __restrict__ qhat,
                                                   const unsigned short* __restrict__ varr,
                                                   const unsigned short* __restrict__ kvT,
                                                   const float* __restrict__ wdconv,
                                                   __hip_bfloat16* __restrict__ outpre) {
    const int st = blockIdx.x;                 // 0..31
    const int bh = blockIdx.y;                 // 0..191
    const int b = bh / 12, h = bh % 12;
    const int s0 = st * 128;
    const int t = threadIdx.x, w = t >> 6, lane = t & 63;
    const int quad = lane >> 4, l16 = lane & 15;

    __shared__ __align__(16) unsigned short vt[136 * 64];  // rows s0-4 .. s0+131
    __shared__ float oL[128 * 65];

    // stage v tile with halo (zero OOB)
    const size_t vb = (size_t)bh * 4096;
#pragma unroll
    for (int i = 0; i < 5; i++) {
        int c = t + i * 256;                   // chunk of 8 elems; 1088 total
        if (c < 1088) {
            int row = c >> 3, off = (c & 7) * 8;
            int gs = s0 - 4 + row;
            bf16x8 vv = {};
            if ((unsigned)gs < 4096u) vv = *(const bf16x8*)(varr + (vb + gs) * 64 + off);
            *(bf16x8*)&vt[row * 64 + off] = vv;
        }
    }

    // B fragments from kvT (global)
    bf16x8 bfr[2][4];
#pragma unroll
    for (int ks = 0; ks < 2; ks++)
#pragma unroll
        for (int j = 0; j < 4; j++)
            bfr[ks][j] = *(const bf16x8*)(kvT + (size_t)bh * 4096 + (j * 16 + l16) * 64 + ks * 32 + quad * 8);

    // MFMA: rows w*32 + i*16
    f32x4 acc[2][4] = {};
#pragma unroll
    for (int i = 0; i < 2; i++) {
#pragma unroll
        for (int ks = 0; ks < 2; ks++) {
            bf16x8 af = *(const bf16x8*)(qhat + (vb + s0 + w * 32 + i * 16 + l16) * 64 + ks * 32 + quad * 8);
#pragma unroll
            for (int j = 0; j < 4; j++)
                acc[i][j] = __builtin_amdgcn_mfma_f32_16x16x32_bf16(af, bfr[ks][j], acc[i][j], 0, 0, 0);
        }
    }
    __syncthreads();

    // epilogue 1: o = 0.5 v + (1/pi) attn; row-norm; write oL
    const float inv_pi = 0.3183098861837907f;
#pragma unroll
    for (int i = 0; i < 2; i++) {
        float o[4][4];
#pragma unroll
        for (int r = 0; r < 4; r++) {
            int rl = w * 32 + i * 16 + quad * 4 + r;
#pragma unroll
            for (int j = 0; j < 4; j++) {
                float vval = b2f(vt[(rl + 4) * 64 + j * 16 + l16]);
                o[j][r] = 0.5f * vval + inv_pi * acc[i][j][r];
            }
            float ss = o[0][r]*o[0][r] + o[1][r]*o[1][r] + o[2][r]*o[2][r] + o[3][r]*o[3][r];
            ss += __shfl_xor(ss, 1, 64);
            ss += __shfl_xor(ss, 2, 64);
            ss += __shfl_xor(ss, 4, 64);
            ss += __shfl_xor(ss, 8, 64);
            float sc = rsqrtf(ss);
#pragma unroll
            for (int j = 0; j < 4; j++)
                oL[rl * 65 + j * 16 + l16] = o[j][r] * sc;
        }
    }
    __syncthreads();

    // epilogue 2: + depthwise conv, store bf16 row-major [b,s,768]
    float wc[9];
#pragma unroll
    for (int j = 0; j < 9; j++) wc[j] = wdconv[h * 9 + j];
#pragma unroll
    for (int i = 0; i < 32; i++) {
        int c = t + i * 256;                   // s_local*64 + f
        int sl = c >> 6, f = c & 63;
        float cc = 0.f;
#pragma unroll
        for (int j = 0; j < 9; j++) cc += wc[j] * b2f(vt[(sl + j) * 64 + f]);
        float oo = oL[sl * 65 + f] + cc;
        outpre[(size_t)(b * 4096 + s0 + sl) * 768 + h * 64 + f] = __float2bfloat16(oo);
    }
}

// ---------------------------------------------------------------- launch
extern "C" void kernel_launch(void* const* d_in, const int* in_sizes, int n_in,
                              void* d_out, int out_size, void* d_ws, size_t ws_size,
                              hipStream_t stream) {
    const float* x      = (const float*)d_in[0];
    const float* w_qkv  = (const float*)d_in[1];
    const float* b_qkv  = (const float*)d_in[2];
    const float* w_proj = (const float*)d_in[3];
    const float* b_proj = (const float*)d_in[4];
    const float* w_dc   = (const float*)d_in[5];
    float* out = (float*)d_out;

    char* ws = (char*)d_ws;
    unsigned short* xb      = (unsigned short*)(ws + 0);             // 100,663,296 (reused as outpre)
    unsigned short* wqkvb   = (unsigned short*)(ws + 100663296);     //   3,538,944
    unsigned short* wprojb  = (unsigned short*)(ws + 104202240);     //   1,179,648
    unsigned short* qhat    = (unsigned short*)(ws + 105381888);     // 100,663,296
    unsigned short* khat    = (unsigned short*)(ws + 206045184);     // 100,663,296
    unsigned short* varr    = (unsigned short*)(ws + 306708480);     // 100,663,296
    float* kvpart           = (float*)(ws + 407371776);              //  12,582,912
    unsigned short* kvT     = (unsigned short*)(ws + 419954688);     //   1,572,864

    const int NX = 16 * 4096 * 768;
    const int NWQ = 2304 * 768;
    const int NWP = 768 * 768;

    cvt_bf16<<<NX / 1024, 256, 0, stream>>>(x, xb, NX);
    cvt_bf16<<<NWQ / 1024, 256, 0, stream>>>(w_qkv, wqkvb, NWQ);
    cvt_bf16<<<NWP / 1024, 256, 0, stream>>>(w_proj, wprojb, NWP);

    // qkv projection + norm epilogue: grid 9 x 256 = 2304 blocks (%8 == 0)
    gemm256<1><<<dim3(2304 / 256, 65536 / 256), 512, 0, stream>>>(
        xb, wqkvb, b_qkv, nullptr, qhat, khat, varr, 2304);

    kv_kernel<<<192 * 4, 256, 0, stream>>>(khat, varr, kvpart);

    kvred_kernel<<<192, 256, 0, stream>>>(kvpart, kvT);

    attn_kernel<<<dim3(32, 192), 256, 0, stream>>>(qhat, varr, kvT, w_dc, (__hip_bfloat16*)xb);

    // output projection: grid 3 x 256 = 768 blocks (%8 == 0)
    gemm256<0><<<dim3(768 / 256, 65536 / 256), 512, 0, stream>>>(
        xb, wprojb, b_proj, out, nullptr, nullptr, nullptr, 768);
}